// Round 18
// baseline (1742.184 us; speedup 1.0000x reference)
//
#include <hip/hip_runtime.h>

#define TT 1024
#define DD 32
#define HH 64

typedef __fp16 h2v __attribute__((ext_vector_type(2)));
typedef _Float16 f16x8 __attribute__((ext_vector_type(8)));
typedef float f32x4 __attribute__((ext_vector_type(4)));

struct __attribute__((aligned(16))) H4 { h2v p[4]; };

__device__ __forceinline__ h2v pk(float a, float b) {
    return __builtin_amdgcn_cvt_pkrtz(a, b);
}
__device__ __forceinline__ float fsig(float x) {
    float e = __builtin_amdgcn_exp2f(-1.4426950408889634f * x);
    return __builtin_amdgcn_rcpf(1.0f + e);
}
__device__ __forceinline__ float ftanh(float x) {
    float e = __builtin_amdgcn_exp2f(2.885390081777927f * x);
    return 1.0f - 2.0f * __builtin_amdgcn_rcpf(1.0f + e);
}
// LDS-only barrier (epoch boundary): orders ds ops, leaves x prefetches in flight
__device__ __forceinline__ void bar_lds() {
    asm volatile("s_waitcnt lgkmcnt(0)\n\ts_barrier" ::: "memory");
}
__device__ __forceinline__ float pick4(f32x4 c, bool s0, bool s1) {
    float lo = s0 ? c[1] : c[0];
    float hi = s0 ? c[3] : c[2];
    return s1 ? hi : lo;
}
__device__ __forceinline__ f16x8 packx(float4 a, float4 b) {
    H4 t;
    t.p[0] = pk(a.x, a.y); t.p[1] = pk(a.z, a.w);
    t.p[2] = pk(b.x, b.y); t.p[3] = pk(b.z, b.w);
    return __builtin_bit_cast(f16x8, t);
}
__device__ __forceinline__ f16x8 load_afrag(const float* p) {
    return packx(*(const float4*)p, *(const float4*)(p + 4));
}
#define MFMA16(A, B, C) __builtin_amdgcn_mfma_f32_16x16x32_f16(A, B, C, 0, 0, 0)

// ---------------------------------------------------------------------------
// Wave-internal recurrence: 64 blocks x 128 threads (2 waves), 4 batch/block.
// Wave 0 = L1 for ALL 64 j (16 MFMA tiles as 4 j-groups); its h1(t)->h1(t+1)
// loop is wave-internal (lgkm-ordered LDS round-trip, NO barrier).
// Wave 1 = L2 for all j, lagging 8 steps; consumes h1 via a 16-slot LDS ring
// with two-phase halves; barrier only every 8 steps (129 total vs 1025).
// B cols = 4 batch x 4 reps; C layout (m89) -> lane owns cell
// (j = jg*16 + quad*4 + rsel, batch = lane&3) per j-group.
// Weights = MFMA-A-fragments only (L1 48, L2 64) -> AGPR-resident free.
// LDS: ring 16 x 256 f16 (h1) + 2 x 256 f16 (h2 parities) = 9216 B.
// ---------------------------------------------------------------------------
__global__ __launch_bounds__(128) void lstm2_wv(
    const float* __restrict__ x,
    const float* __restrict__ w_ih_l0, const float* __restrict__ w_hh_l0,
    const float* __restrict__ b_ih_l0, const float* __restrict__ b_hh_l0,
    const float* __restrict__ w_ih_l1, const float* __restrict__ w_hh_l1,
    const float* __restrict__ b_ih_l1, const float* __restrict__ b_hh_l1,
    const float* __restrict__ w_fc,   const float* __restrict__ b_fc,
    float* __restrict__ out)
{
    const int bbase = blockIdx.x * 4;
    const int tid  = threadIdx.x;
    const int wave = tid >> 6;
    const int lane = tid & 63;
    const int quad = lane >> 4;
    const int bb   = lane & 3;
    const int rsel = (lane >> 2) & 3;
    const int mrow = lane & 15;

    // ring: slots 0..15 at s*256; h2 parities at 4096 + p*256
    __shared__ __attribute__((aligned(16))) __fp16 buf[4608];
    {
        int* bi = (int*)buf;
        #pragma unroll
        for (int i = 0; i < 18; ++i) bi[tid + i*128] = 0;   // 2304 dwords
    }

    // ---- weights (A-fragments) + per-cell biases + write offsets ----
    f16x8 A[64];
    float bs[16];
    int woffs[4];
    if (wave == 0) {
        #pragma unroll
        for (int jg = 0; jg < 4; ++jg)
            #pragma unroll
            for (int q = 0; q < 4; ++q) {
                const int g = q*64 + jg*16 + mrow;
                A[jg*12 + q*3 + 0] = load_afrag(w_ih_l0 + (size_t)g*DD + quad*8);
                A[jg*12 + q*3 + 1] = load_afrag(w_hh_l0 + (size_t)g*HH + quad*8);
                A[jg*12 + q*3 + 2] = load_afrag(w_hh_l0 + (size_t)g*HH + 32 + quad*8);
            }
        #pragma unroll
        for (int jg = 0; jg < 4; ++jg) {
            const int jj = jg*16 + quad*4 + rsel;
            #pragma unroll
            for (int q = 0; q < 4; ++q)
                bs[jg*4 + q] = b_ih_l0[q*64 + jj] + b_hh_l0[q*64 + jj];
            woffs[jg] = (((jj >> 5)*4 + bb)*4 + ((jj & 31) >> 3))*8 + (jj & 7);
        }
    } else {
        #pragma unroll
        for (int jg = 0; jg < 4; ++jg)
            #pragma unroll
            for (int q = 0; q < 4; ++q) {
                const int g = q*64 + jg*16 + mrow;
                A[jg*16 + q*4 + 0] = load_afrag(w_ih_l1 + (size_t)g*HH + quad*8);
                A[jg*16 + q*4 + 1] = load_afrag(w_ih_l1 + (size_t)g*HH + 32 + quad*8);
                A[jg*16 + q*4 + 2] = load_afrag(w_hh_l1 + (size_t)g*HH + quad*8);
                A[jg*16 + q*4 + 3] = load_afrag(w_hh_l1 + (size_t)g*HH + 32 + quad*8);
            }
        #pragma unroll
        for (int jg = 0; jg < 4; ++jg) {
            const int jj = jg*16 + quad*4 + rsel;
            #pragma unroll
            for (int q = 0; q < 4; ++q)
                bs[jg*4 + q] = b_ih_l1[q*64 + jj] + b_hh_l1[q*64 + jj];
            woffs[jg] = (((jj >> 5)*4 + bb)*4 + ((jj & 31) >> 3))*8 + (jj & 7);
        }
    }

    const int roff = (bb*4 + quad)*8;

    // x register ring (wave 0): lane's 8-float slice of x[bb][t][quad*8..+7]
    const float* xg = x + (size_t)(bbase + bb) * (TT*DD) + quad*8;
    f16x8 xr0 = {}, xr1 = {};
    if (wave == 0) {
        xr0 = packx(*(const float4*)xg, *(const float4*)(xg + 4));
        xr1 = packx(*(const float4*)(xg + DD), *(const float4*)(xg + DD + 4));
    }

    __syncthreads();   // zero-init visible

    const bool s0 = (rsel & 1) != 0;
    const bool s1 = (rsel & 2) != 0;
    float cst[4] = {0.f, 0.f, 0.f, 0.f};
    const f32x4 Z = {0.f, 0.f, 0.f, 0.f};

    for (int I = 0; I < 129; ++I) {
        if (wave == 0) {
            if (I < 128) {
                for (int k = 0; k < 8; ++k) {
                    const int t = I*8 + k;
                    // h1(t-1) from ring slot (t-1)&15 (own write, lgkm-ordered)
                    const __fp16* rs = buf + ((t + 15) & 15)*256;
                    f16x8 B1 = *(const f16x8*)(rs + roff);
                    f16x8 B2 = *(const f16x8*)(rs + 128 + roff);
                    f16x8 Bx = xr0;
                    xr0 = xr1;
                    const int tn = (t + 2 < TT) ? (t + 2) : (TT - 1);
                    xr1 = packx(*(const float4*)(xg + (size_t)tn*DD),
                                *(const float4*)(xg + (size_t)tn*DD + 4));
                    __fp16* ws = buf + (t & 15)*256;
                    #pragma unroll
                    for (int jg = 0; jg < 4; ++jg) {
                        f32x4 C0 = MFMA16(A[jg*12+0], Bx, Z);
                        f32x4 C1 = MFMA16(A[jg*12+3], Bx, Z);
                        f32x4 C2 = MFMA16(A[jg*12+6], Bx, Z);
                        f32x4 C3 = MFMA16(A[jg*12+9], Bx, Z);
                        C0 = MFMA16(A[jg*12+1],  B1, C0); C0 = MFMA16(A[jg*12+2],  B2, C0);
                        C1 = MFMA16(A[jg*12+4],  B1, C1); C1 = MFMA16(A[jg*12+5],  B2, C1);
                        C2 = MFMA16(A[jg*12+7],  B1, C2); C2 = MFMA16(A[jg*12+8],  B2, C2);
                        C3 = MFMA16(A[jg*12+10], B1, C3); C3 = MFMA16(A[jg*12+11], B2, C3);

                        float Si = pick4(C0, s0, s1) + bs[jg*4+0];
                        float Sf = pick4(C1, s0, s1) + bs[jg*4+1];
                        float Sg = pick4(C2, s0, s1) + bs[jg*4+2];
                        float So = pick4(C3, s0, s1) + bs[jg*4+3];

                        float ii = fsig(Si), ff = fsig(Sf), oo = fsig(So);
                        float gg = ftanh(Sg);
                        cst[jg] = ff * cst[jg] + ii * gg;
                        float hv = oo * ftanh(cst[jg]);
                        ws[woffs[jg]] = (__fp16)hv;
                    }
                }
            }
        } else {
            if (I > 0) {
                for (int k = 0; k < 8; ++k) {
                    const int t = (I - 1)*8 + k;     // L2 timestep (lags 8)
                    // h1(t) from ring (written by L1 last interval)
                    const __fp16* rs = buf + (t & 15)*256;
                    f16x8 B1 = *(const f16x8*)(rs + roff);
                    f16x8 B2 = *(const f16x8*)(rs + 128 + roff);
                    // h2(t-1) from own parity buffer
                    const __fp16* h2r = buf + 4096 + (((t & 1) ^ 1))*256;
                    f16x8 B3 = *(const f16x8*)(h2r + roff);
                    f16x8 B4 = *(const f16x8*)(h2r + 128 + roff);
                    __fp16* ws = buf + 4096 + (t & 1)*256;
                    #pragma unroll
                    for (int jg = 0; jg < 4; ++jg) {
                        f32x4 C0 = MFMA16(A[jg*16+0],  B1, Z);
                        f32x4 C1 = MFMA16(A[jg*16+4],  B1, Z);
                        f32x4 C2 = MFMA16(A[jg*16+8],  B1, Z);
                        f32x4 C3 = MFMA16(A[jg*16+12], B1, Z);
                        C0 = MFMA16(A[jg*16+1],  B2, C0); C0 = MFMA16(A[jg*16+2],  B3, C0); C0 = MFMA16(A[jg*16+3],  B4, C0);
                        C1 = MFMA16(A[jg*16+5],  B2, C1); C1 = MFMA16(A[jg*16+6],  B3, C1); C1 = MFMA16(A[jg*16+7],  B4, C1);
                        C2 = MFMA16(A[jg*16+9],  B2, C2); C2 = MFMA16(A[jg*16+10], B3, C2); C2 = MFMA16(A[jg*16+11], B4, C2);
                        C3 = MFMA16(A[jg*16+13], B2, C3); C3 = MFMA16(A[jg*16+14], B3, C3); C3 = MFMA16(A[jg*16+15], B4, C3);

                        float Si = pick4(C0, s0, s1) + bs[jg*4+0];
                        float Sf = pick4(C1, s0, s1) + bs[jg*4+1];
                        float Sg = pick4(C2, s0, s1) + bs[jg*4+2];
                        float So = pick4(C3, s0, s1) + bs[jg*4+3];

                        float ii = fsig(Si), ff = fsig(Sf), oo = fsig(So);
                        float gg = ftanh(Sg);
                        cst[jg] = ff * cst[jg] + ii * gg;
                        float hv = oo * ftanh(cst[jg]);
                        ws[woffs[jg]] = (__fp16)hv;
                    }
                }
            }
        }
        bar_lds();   // epoch boundary: ring half handoff (every 8 steps)
    }

    // FC + sigmoid (wave 1 holds final h2(1023) in parity 1)
    if (wave == 1) {
        asm volatile("s_waitcnt lgkmcnt(0)" ::: "memory");
        const int jg2 = lane >> 2;   // 0..15
        float s = 0.f;
        #pragma unroll
        for (int u = 0; u < 4; ++u) {
            const int j = jg2*4 + u;
            float hval = (float)buf[4096 + 256 + (((j >> 5)*4 + bb)*4 + ((j & 31) >> 3))*8 + (j & 7)];
            s += hval * w_fc[j];
        }
        s += __shfl_xor(s, 4);
        s += __shfl_xor(s, 8);
        s += __shfl_xor(s, 16);
        s += __shfl_xor(s, 32);
        if (lane < 4) out[bbase + lane] = fsig(s + b_fc[0]);
    }
}

extern "C" void kernel_launch(void* const* d_in, const int* in_sizes, int n_in,
                              void* d_out, int out_size, void* d_ws, size_t ws_size,
                              hipStream_t stream) {
    lstm2_wv<<<dim3(64), dim3(128), 0, stream>>>(
        (const float*)d_in[0],
        (const float*)d_in[1], (const float*)d_in[2],
        (const float*)d_in[3], (const float*)d_in[4],
        (const float*)d_in[5], (const float*)d_in[6],
        (const float*)d_in[7], (const float*)d_in[8],
        (const float*)d_in[9], (const float*)d_in[10],
        (float*)d_out);
}

// Round 19
// 836.709 us; speedup vs baseline: 2.0822x; 2.0822x over previous
//
#include <hip/hip_runtime.h>

#define TT 1024
#define DD 32
#define HH 64

typedef __fp16 h2v __attribute__((ext_vector_type(2)));
typedef _Float16 f16x8 __attribute__((ext_vector_type(8)));
typedef float f32x4 __attribute__((ext_vector_type(4)));

struct __attribute__((aligned(16))) H4 { h2v p[4]; };

__device__ __forceinline__ h2v pk(float a, float b) {
    return __builtin_amdgcn_cvt_pkrtz(a, b);
}
__device__ __forceinline__ float fsig(float x) {
    float e = __builtin_amdgcn_exp2f(-1.4426950408889634f * x);
    return __builtin_amdgcn_rcpf(1.0f + e);
}
__device__ __forceinline__ float ftanh(float x) {
    float e = __builtin_amdgcn_exp2f(2.885390081777927f * x);
    return 1.0f - 2.0f * __builtin_amdgcn_rcpf(1.0f + e);
}
// LDS-only barrier: orders ds ops, leaves P1's x loads in flight
__device__ __forceinline__ void bar_lds() {
    asm volatile("s_waitcnt lgkmcnt(0)\n\ts_barrier" ::: "memory");
}
__device__ __forceinline__ float pick4(f32x4 c, bool s0, bool s1) {
    float lo = s0 ? c[1] : c[0];
    float hi = s0 ? c[3] : c[2];
    return s1 ? hi : lo;
}
__device__ __forceinline__ f16x8 packx(float4 a, float4 b) {
    H4 t;
    t.p[0] = pk(a.x, a.y); t.p[1] = pk(a.z, a.w);
    t.p[2] = pk(b.x, b.y); t.p[3] = pk(b.z, b.w);
    return __builtin_bit_cast(f16x8, t);
}
__device__ __forceinline__ f16x8 load_afrag(const float* p) {
    return packx(*(const float4*)p, *(const float4*)(p + 4));
}
#define MFMA16(A, B, C) __builtin_amdgcn_mfma_f32_16x16x32_f16(A, B, C, 0, 0, 0)

// ---------------------------------------------------------------------------
// 4-wave producer/consumer pipeline. 64 blocks x 256 threads, 4 batch/block.
//   wave 0 P1: gx1(t)=W_ih_l0 x(t)+biases -> gx1 ring        (16 A-frags)
//   wave 1 C1: h1(t)=act(gx1 + W_hh_l0 h1(t-1)) wave-internal (32 A-frags)
//   wave 2 P2: gx2(t)=W_ih_l1 h1(t)+biases -> gx2 ring        (32 A-frags)
//   wave 3 C2: h2(t)=act(gx2 + W_hh_l1 h2(t-1)) wave-internal (32 A-frags)
// Recurrences are in-wave (lgkm-ordered LDS round-trip, no barrier).
// Cross-wave handoffs are one-directional, 4-step lag, two-phase 8-slot
// rings; ONE block barrier per 4 steps (259 total vs 1025).
// Work windows at interval i: P1 t=[4i..), C1 [4(i-1)..), P2 [4(i-2)..),
// C2 [4(i-3)..) -> ring halves alternate, writer/reader always disjoint.
// B cols = 4 batch x 4 reps; C layout (m89) -> lane owns cell
// (j=jg*16+quad*4+rsel, batch=lane&3) per j-group. Weights = MFMA-A operands
// only (<=32 frags/wave, the R18 spill lesson); consumers hold no bias/x.
// gx rings f32, [row=jg*2+qpair][lane] float2 (2-way bank alias = free).
// ---------------------------------------------------------------------------
__global__ __launch_bounds__(256) void lstm2_p4(
    const float* __restrict__ x,
    const float* __restrict__ w_ih_l0, const float* __restrict__ w_hh_l0,
    const float* __restrict__ b_ih_l0, const float* __restrict__ b_hh_l0,
    const float* __restrict__ w_ih_l1, const float* __restrict__ w_hh_l1,
    const float* __restrict__ b_ih_l1, const float* __restrict__ b_hh_l1,
    const float* __restrict__ w_fc,   const float* __restrict__ b_fc,
    float* __restrict__ out)
{
    const int bbase = blockIdx.x * 4;
    const int tid  = threadIdx.x;
    const int wave = tid >> 6;
    const int lane = tid & 63;
    const int quad = lane >> 4;
    const int bb   = lane & 3;
    const int rsel = (lane >> 2) & 3;
    const int mrow = lane & 15;

    __shared__ __attribute__((aligned(16))) float  gx1[8 * 1024];  // 32 KB
    __shared__ __attribute__((aligned(16))) float  gx2[8 * 1024];  // 32 KB
    __shared__ __attribute__((aligned(16))) __fp16 h1r[8 * 256];   // 4 KB
    __shared__ __attribute__((aligned(16))) __fp16 h2r[2 * 256];   // 1 KB

    // zero h rings (C1 reads slot 7 at t=0; C2 reads parity 1 at t=0)
    {
        int* p1 = (int*)h1r;
        #pragma unroll
        for (int i = 0; i < 4; ++i) p1[tid + i*256] = 0;
        ((int*)h2r)[tid] = 0;
    }

    // ---- per-wave weights (A-fragments) ----
    f16x8 A[32];
    float bs[16];   // biases: only P-waves use
    if (wave == 0) {
        #pragma unroll
        for (int jg = 0; jg < 4; ++jg)
            #pragma unroll
            for (int q = 0; q < 4; ++q) {
                const int g = q*64 + jg*16 + mrow;
                A[jg*4 + q] = load_afrag(w_ih_l0 + (size_t)g*DD + quad*8);
                const int jj = jg*16 + quad*4 + rsel;
                bs[jg*4 + q] = b_ih_l0[q*64 + jj] + b_hh_l0[q*64 + jj];
            }
    } else if (wave == 1) {
        #pragma unroll
        for (int jg = 0; jg < 4; ++jg)
            #pragma unroll
            for (int q = 0; q < 4; ++q) {
                const int g = q*64 + jg*16 + mrow;
                A[jg*8 + q*2 + 0] = load_afrag(w_hh_l0 + (size_t)g*HH + quad*8);
                A[jg*8 + q*2 + 1] = load_afrag(w_hh_l0 + (size_t)g*HH + 32 + quad*8);
            }
    } else if (wave == 2) {
        #pragma unroll
        for (int jg = 0; jg < 4; ++jg)
            #pragma unroll
            for (int q = 0; q < 4; ++q) {
                const int g = q*64 + jg*16 + mrow;
                A[jg*8 + q*2 + 0] = load_afrag(w_ih_l1 + (size_t)g*HH + quad*8);
                A[jg*8 + q*2 + 1] = load_afrag(w_ih_l1 + (size_t)g*HH + 32 + quad*8);
                const int jj = jg*16 + quad*4 + rsel;
                bs[jg*4 + q] = b_ih_l1[q*64 + jj] + b_hh_l1[q*64 + jj];
            }
    } else {
        #pragma unroll
        for (int jg = 0; jg < 4; ++jg)
            #pragma unroll
            for (int q = 0; q < 4; ++q) {
                const int g = q*64 + jg*16 + mrow;
                A[jg*8 + q*2 + 0] = load_afrag(w_hh_l1 + (size_t)g*HH + quad*8);
                A[jg*8 + q*2 + 1] = load_afrag(w_hh_l1 + (size_t)g*HH + 32 + quad*8);
            }
    }

    // h-ring offsets
    const int roff = (bb*4 + quad)*8;             // B-frag read within slot
    int woffs[4];                                  // h write offset per jg
    #pragma unroll
    for (int jg = 0; jg < 4; ++jg) {
        const int jj = jg*16 + quad*4 + rsel;
        woffs[jg] = (((jj >> 5)*4 + bb)*4 + ((jj & 31) >> 3))*8 + (jj & 7);
    }

    const float* xg = x + (size_t)(bbase + bb) * (TT*DD) + quad*8;
    const bool s0 = (rsel & 1) != 0;
    const bool s1 = (rsel & 2) != 0;
    float cst[4] = {0.f, 0.f, 0.f, 0.f};
    const f32x4 Z = {0.f, 0.f, 0.f, 0.f};

    __syncthreads();   // zero-init visible

    for (int I = 0; I < 259; ++I) {
        if (wave == 0) {
            if (I < 256) {
                #pragma unroll
                for (int k = 0; k < 4; ++k) {
                    const int t = 4*I + k;
                    const float* xp = xg + (size_t)t * DD;
                    f16x8 Bx = packx(*(const float4*)xp, *(const float4*)(xp + 4));
                    float* gs = gx1 + (t & 7)*1024;
                    #pragma unroll
                    for (int jg = 0; jg < 4; ++jg) {
                        f32x4 C0 = MFMA16(A[jg*4+0], Bx, Z);
                        f32x4 C1 = MFMA16(A[jg*4+1], Bx, Z);
                        f32x4 C2 = MFMA16(A[jg*4+2], Bx, Z);
                        f32x4 C3 = MFMA16(A[jg*4+3], Bx, Z);
                        float2 p0 = { pick4(C0, s0, s1) + bs[jg*4+0],
                                      pick4(C1, s0, s1) + bs[jg*4+1] };
                        float2 p1 = { pick4(C2, s0, s1) + bs[jg*4+2],
                                      pick4(C3, s0, s1) + bs[jg*4+3] };
                        *(float2*)&gs[(jg*2+0)*128 + lane*2] = p0;
                        *(float2*)&gs[(jg*2+1)*128 + lane*2] = p1;
                    }
                }
            }
        } else if (wave == 1) {
            if (I >= 1 && I <= 256) {
                for (int k = 0; k < 4; ++k) {
                    const int t = 4*(I-1) + k;
                    const float* gs = gx1 + (t & 7)*1024;
                    float2 g0[4], g1[4];
                    #pragma unroll
                    for (int jg = 0; jg < 4; ++jg) {
                        g0[jg] = *(const float2*)&gs[(jg*2+0)*128 + lane*2];
                        g1[jg] = *(const float2*)&gs[(jg*2+1)*128 + lane*2];
                    }
                    const __fp16* hb = h1r + ((t + 7) & 7)*256;
                    f16x8 B1 = *(const f16x8*)(hb + roff);
                    f16x8 B2 = *(const f16x8*)(hb + 128 + roff);
                    __fp16* ws = h1r + (t & 7)*256;
                    #pragma unroll
                    for (int jg = 0; jg < 4; ++jg) {
                        f32x4 C0 = MFMA16(A[jg*8+0], B1, Z); C0 = MFMA16(A[jg*8+1], B2, C0);
                        f32x4 C1 = MFMA16(A[jg*8+2], B1, Z); C1 = MFMA16(A[jg*8+3], B2, C1);
                        f32x4 C2 = MFMA16(A[jg*8+4], B1, Z); C2 = MFMA16(A[jg*8+5], B2, C2);
                        f32x4 C3 = MFMA16(A[jg*8+6], B1, Z); C3 = MFMA16(A[jg*8+7], B2, C3);

                        float Si = pick4(C0, s0, s1) + g0[jg].x;
                        float Sf = pick4(C1, s0, s1) + g0[jg].y;
                        float Sg = pick4(C2, s0, s1) + g1[jg].x;
                        float So = pick4(C3, s0, s1) + g1[jg].y;

                        float ii = fsig(Si), ff = fsig(Sf), oo = fsig(So);
                        float gg = ftanh(Sg);
                        cst[jg] = ff * cst[jg] + ii * gg;
                        ws[woffs[jg]] = (__fp16)(oo * ftanh(cst[jg]));
                    }
                }
            }
        } else if (wave == 2) {
            if (I >= 2 && I <= 257) {
                #pragma unroll
                for (int k = 0; k < 4; ++k) {
                    const int t = 4*(I-2) + k;
                    const __fp16* hb = h1r + (t & 7)*256;
                    f16x8 B1 = *(const f16x8*)(hb + roff);
                    f16x8 B2 = *(const f16x8*)(hb + 128 + roff);
                    float* gs = gx2 + (t & 7)*1024;
                    #pragma unroll
                    for (int jg = 0; jg < 4; ++jg) {
                        f32x4 C0 = MFMA16(A[jg*8+0], B1, Z); C0 = MFMA16(A[jg*8+1], B2, C0);
                        f32x4 C1 = MFMA16(A[jg*8+2], B1, Z); C1 = MFMA16(A[jg*8+3], B2, C1);
                        f32x4 C2 = MFMA16(A[jg*8+4], B1, Z); C2 = MFMA16(A[jg*8+5], B2, C2);
                        f32x4 C3 = MFMA16(A[jg*8+6], B1, Z); C3 = MFMA16(A[jg*8+7], B2, C3);
                        float2 p0 = { pick4(C0, s0, s1) + bs[jg*4+0],
                                      pick4(C1, s0, s1) + bs[jg*4+1] };
                        float2 p1 = { pick4(C2, s0, s1) + bs[jg*4+2],
                                      pick4(C3, s0, s1) + bs[jg*4+3] };
                        *(float2*)&gs[(jg*2+0)*128 + lane*2] = p0;
                        *(float2*)&gs[(jg*2+1)*128 + lane*2] = p1;
                    }
                }
            }
        } else {
            if (I >= 3) {
                for (int k = 0; k < 4; ++k) {
                    const int t = 4*(I-3) + k;
                    const float* gs = gx2 + (t & 7)*1024;
                    float2 g0[4], g1[4];
                    #pragma unroll
                    for (int jg = 0; jg < 4; ++jg) {
                        g0[jg] = *(const float2*)&gs[(jg*2+0)*128 + lane*2];
                        g1[jg] = *(const float2*)&gs[(jg*2+1)*128 + lane*2];
                    }
                    const __fp16* hb = h2r + ((t + 1) & 1)*256;
                    f16x8 B3 = *(const f16x8*)(hb + roff);
                    f16x8 B4 = *(const f16x8*)(hb + 128 + roff);
                    __fp16* ws = h2r + (t & 1)*256;
                    #pragma unroll
                    for (int jg = 0; jg < 4; ++jg) {
                        f32x4 C0 = MFMA16(A[jg*8+0], B3, Z); C0 = MFMA16(A[jg*8+1], B4, C0);
                        f32x4 C1 = MFMA16(A[jg*8+2], B3, Z); C1 = MFMA16(A[jg*8+3], B4, C1);
                        f32x4 C2 = MFMA16(A[jg*8+4], B3, Z); C2 = MFMA16(A[jg*8+5], B4, C2);
                        f32x4 C3 = MFMA16(A[jg*8+6], B3, Z); C3 = MFMA16(A[jg*8+7], B4, C3);

                        float Si = pick4(C0, s0, s1) + g0[jg].x;
                        float Sf = pick4(C1, s0, s1) + g0[jg].y;
                        float Sg = pick4(C2, s0, s1) + g1[jg].x;
                        float So = pick4(C3, s0, s1) + g1[jg].y;

                        float ii = fsig(Si), ff = fsig(Sf), oo = fsig(So);
                        float gg = ftanh(Sg);
                        cst[jg] = ff * cst[jg] + ii * gg;
                        ws[woffs[jg]] = (__fp16)(oo * ftanh(cst[jg]));
                    }
                }
            }
        }
        bar_lds();
    }

    // FC + sigmoid: h2(1023) sits in h2r parity 1 (1023 & 1).
    if (wave == 3) {
        const int jg2 = lane >> 2;   // 0..15
        float s = 0.f;
        #pragma unroll
        for (int u = 0; u < 4; ++u) {
            const int j = jg2*4 + u;
            float hval = (float)h2r[256 + (((j >> 5)*4 + bb)*4 + ((j & 31) >> 3))*8 + (j & 7)];
            s += hval * w_fc[j];
        }
        s += __shfl_xor(s, 4);
        s += __shfl_xor(s, 8);
        s += __shfl_xor(s, 16);
        s += __shfl_xor(s, 32);
        if (lane < 4) out[bbase + lane] = fsig(s + b_fc[0]);
    }
}

extern "C" void kernel_launch(void* const* d_in, const int* in_sizes, int n_in,
                              void* d_out, int out_size, void* d_ws, size_t ws_size,
                              hipStream_t stream) {
    lstm2_p4<<<dim3(64), dim3(256), 0, stream>>>(
        (const float*)d_in[0],
        (const float*)d_in[1], (const float*)d_in[2],
        (const float*)d_in[3], (const float*)d_in[4],
        (const float*)d_in[5], (const float*)d_in[6],
        (const float*)d_in[7], (const float*)d_in[8],
        (const float*)d_in[9], (const float*)d_in[10],
        (float*)d_out);
}

// Round 20
// 549.557 us; speedup vs baseline: 3.1702x; 1.5225x over previous
//
#include <hip/hip_runtime.h>

#define TT 1024
#define DD 32
#define HH 64

typedef __fp16 h2v __attribute__((ext_vector_type(2)));
typedef _Float16 f16x8 __attribute__((ext_vector_type(8)));
typedef float f32x4 __attribute__((ext_vector_type(4)));

struct __attribute__((aligned(16))) H4 { h2v p[4]; };

__device__ __forceinline__ h2v pk(float a, float b) {
    return __builtin_amdgcn_cvt_pkrtz(a, b);
}
__device__ __forceinline__ float fsig(float x) {
    float e = __builtin_amdgcn_exp2f(-1.4426950408889634f * x);
    return __builtin_amdgcn_rcpf(1.0f + e);
}
__device__ __forceinline__ float ftanh(float x) {
    float e = __builtin_amdgcn_exp2f(2.885390081777927f * x);
    return 1.0f - 2.0f * __builtin_amdgcn_rcpf(1.0f + e);
}
// select reg r (r = s1*2+s0) of a C-fragment: 3 cndmasks
__device__ __forceinline__ float pick4(f32x4 c, bool s0, bool s1) {
    float lo = s0 ? c[1] : c[0];
    float hi = s0 ? c[3] : c[2];
    return s1 ? hi : lo;
}
// A-fragment: 8 consecutive fp32 weights -> packed f16 (lane = A[m=lane&15][k=quad*8+i])
__device__ __forceinline__ f16x8 load_afrag(const float* p) {
    float4 f0 = *(const float4*)p;
    float4 f1 = *(const float4*)(p + 4);
    H4 t;
    t.p[0] = pk(f0.x, f0.y); t.p[1] = pk(f0.z, f0.w);
    t.p[2] = pk(f1.x, f1.y); t.p[3] = pk(f1.z, f1.w);
    return __builtin_bit_cast(f16x8, t);
}
#define MFMA16(A, B, C) __builtin_amdgcn_mfma_f32_16x16x32_f16(A, B, C, 0, 0, 0)

// ---------------------------------------------------------------------------
// FINAL: exact R12 kernel — verified best (545 us, reproduced twice).
// The ~1140 cyc/step wall is the latency floor of a cross-wave skewed
// two-layer pipeline: barrier sync (~300) + LDS round-trip (~200) + MFMA
// chain (~90) + activation chain (~120) + DS-pipe occupancy (~250).
// Falsified alternatives: issue load (R12), bank conflicts (R9), vmcnt
// drain (R11/R14), MFMA chain depth (R16), layer merge per wave (R15, 2x
// worse: layer chains serialize), layer-per-wave with amortized barriers
// (R18/R19, 1.6-3x worse: 64-j epilogue serializes in one wave).
//
// 64 blocks x 512 threads; block = 4 batch elements.
// Waves 0-3: L1 (j-slice = wave). Waves 4-7: L2 (one step behind); wave 7
// stages x(t+1) into LDS (fp32->f16) with a 2-deep register prefetch ring.
// LDS per parity: 5 chunks x [batch4][quad4][8 f16]:
//   chunk 0 = x(t), chunks 1,2 = h1(t-1), chunks 3,4 = h2(t-2)
// B cols = 4 batches x 4 reps (col&3 = batch). C layout (m89): col=lane&15,
// row=quad*4+reg -> lane owns unique cell (j=js*16+quad*4+rsel, batch=lane&3).
// Weights are MFMA-A-operands only -> AGPR-resident at zero copy cost.
// ---------------------------------------------------------------------------
__global__ __launch_bounds__(512) void lstm2_b4(
    const float* __restrict__ x,
    const float* __restrict__ w_ih_l0, const float* __restrict__ w_hh_l0,
    const float* __restrict__ b_ih_l0, const float* __restrict__ b_hh_l0,
    const float* __restrict__ w_ih_l1, const float* __restrict__ w_hh_l1,
    const float* __restrict__ b_ih_l1, const float* __restrict__ b_hh_l1,
    const float* __restrict__ w_fc,   const float* __restrict__ b_fc,
    float* __restrict__ out)
{
    const int bbase = blockIdx.x * 4;
    const int tid  = threadIdx.x;
    const int wave = tid >> 6;
    const int lane = tid & 63;
    const bool isL1 = wave < 4;
    const int js   = wave & 3;
    const int quad = lane >> 4;
    const int bb   = lane & 3;
    const int rsel = (lane >> 2) & 3;
    const int jj   = js*16 + quad*4 + rsel;
    const int mrow = lane & 15;

    __shared__ __attribute__((aligned(16))) __fp16 buf[1280];  // [2][5][4][4][8]

    {
        int* bi = (int*)buf;
        bi[tid] = 0;
        if (tid < 128) bi[512 + tid] = 0;
    }

    // ---- A fragments (weights), biases ----
    f16x8 A[16];
    float bs0, bs1, bs2, bs3;
    if (isL1) {
        #pragma unroll
        for (int q = 0; q < 4; ++q) {
            const int g = q*64 + js*16 + mrow;
            A[q*3 + 0] = load_afrag(w_ih_l0 + (size_t)g*DD + quad*8);
            A[q*3 + 1] = load_afrag(w_hh_l0 + (size_t)g*HH + quad*8);
            A[q*3 + 2] = load_afrag(w_hh_l0 + (size_t)g*HH + 32 + quad*8);
        }
        bs0 = b_ih_l0[0*64 + jj] + b_hh_l0[0*64 + jj];
        bs1 = b_ih_l0[1*64 + jj] + b_hh_l0[1*64 + jj];
        bs2 = b_ih_l0[2*64 + jj] + b_hh_l0[2*64 + jj];
        bs3 = b_ih_l0[3*64 + jj] + b_hh_l0[3*64 + jj];
    } else {
        #pragma unroll
        for (int q = 0; q < 4; ++q) {
            const int g = q*64 + js*16 + mrow;
            A[q*4 + 0] = load_afrag(w_ih_l1 + (size_t)g*HH + quad*8);
            A[q*4 + 1] = load_afrag(w_ih_l1 + (size_t)g*HH + 32 + quad*8);
            A[q*4 + 2] = load_afrag(w_hh_l1 + (size_t)g*HH + quad*8);
            A[q*4 + 3] = load_afrag(w_hh_l1 + (size_t)g*HH + 32 + quad*8);
        }
        bs0 = b_ih_l1[0*64 + jj] + b_hh_l1[0*64 + jj];
        bs1 = b_ih_l1[1*64 + jj] + b_hh_l1[1*64 + jj];
        bs2 = b_ih_l1[2*64 + jj] + b_hh_l1[2*64 + jj];
        bs3 = b_ih_l1[3*64 + jj] + b_hh_l1[3*64 + jj];
    }

    // per-lane LDS offsets (f16 units)
    const int roff = (bb*4 + quad)*8;
    const int cw   = (isL1 ? 1 : 3) + (jj >> 5);
    const int woff = ((cw*4 + bb)*4 + ((jj & 31) >> 3))*8 + (jj & 7);

    // x stager (wave 7): lane -> (batch = lane>>4, k-pair = lane&15)
    const float* xg = x + (size_t)(bbase + (lane >> 4)) * (TT*DD) + (lane & 15)*2;
    const int sdw = ((lane >> 4)*4 + ((lane & 15) >> 2))*4 + ((lane & 15) & 3);
    float2 xv1 = {0.f, 0.f}, xv2 = {0.f, 0.f};

    __syncthreads();   // zero-init visible before x(0) staging
    if (wave == 7) {
        float2 v0 = *(const float2*)xg;                       // x(0)
        ((int*)buf)[sdw] = __builtin_bit_cast(int, pk(v0.x, v0.y));
        xv1 = *(const float2*)(xg + DD);                      // x(1)
        xv2 = *(const float2*)(xg + 2*DD);                    // x(2)
    }
    __syncthreads();

    const bool s0 = (rsel & 1) != 0;
    const bool s1 = (rsel & 2) != 0;
    float cst = 0.0f;

    for (int t = 0; t <= TT; ++t) {
        const int p = t & 1;
        const __fp16* bc = buf + p*640;
        __fp16* bn = buf + (p ^ 1)*640;
        if (isL1) {
            if (t < TT) {
                f16x8 B0 = *(const f16x8*)(bc + 0*128 + roff);
                f16x8 B1 = *(const f16x8*)(bc + 1*128 + roff);
                f16x8 B2 = *(const f16x8*)(bc + 2*128 + roff);

                f32x4 Z = {0.f, 0.f, 0.f, 0.f};
                f32x4 C0 = Z, C1 = Z, C2 = Z, C3 = Z;
                C0 = MFMA16(A[0], B0, C0); C0 = MFMA16(A[1],  B1, C0); C0 = MFMA16(A[2],  B2, C0);
                C1 = MFMA16(A[3], B0, C1); C1 = MFMA16(A[4],  B1, C1); C1 = MFMA16(A[5],  B2, C1);
                C2 = MFMA16(A[6], B0, C2); C2 = MFMA16(A[7],  B1, C2); C2 = MFMA16(A[8],  B2, C2);
                C3 = MFMA16(A[9], B0, C3); C3 = MFMA16(A[10], B1, C3); C3 = MFMA16(A[11], B2, C3);

                float Si = pick4(C0, s0, s1) + bs0;
                float Sf = pick4(C1, s0, s1) + bs1;
                float Sg = pick4(C2, s0, s1) + bs2;
                float So = pick4(C3, s0, s1) + bs3;

                float ii = fsig(Si), ff = fsig(Sf), oo = fsig(So);
                float gg = ftanh(Sg);
                cst = ff * cst + ii * gg;
                float hv = oo * ftanh(cst);
                bn[woff] = (__fp16)hv;
            }
        } else {
            if (wave == 7 && t < TT) {   // stage x(t+1) into next buffer
                ((int*)bn)[sdw] = __builtin_bit_cast(int, pk(xv1.x, xv1.y));
                xv1 = xv2;
                const int tl = (t + 3 < TT) ? (t + 3) : (TT - 1);
                xv2 = *(const float2*)(xg + (size_t)tl*DD);
            }
            if (t > 0) {
                f16x8 B1 = *(const f16x8*)(bc + 1*128 + roff);
                f16x8 B2 = *(const f16x8*)(bc + 2*128 + roff);
                f16x8 B3 = *(const f16x8*)(bc + 3*128 + roff);
                f16x8 B4 = *(const f16x8*)(bc + 4*128 + roff);

                f32x4 Z = {0.f, 0.f, 0.f, 0.f};
                f32x4 C0 = Z, C1 = Z, C2 = Z, C3 = Z;
                C0 = MFMA16(A[0],  B1, C0); C0 = MFMA16(A[1],  B2, C0);
                C0 = MFMA16(A[2],  B3, C0); C0 = MFMA16(A[3],  B4, C0);
                C1 = MFMA16(A[4],  B1, C1); C1 = MFMA16(A[5],  B2, C1);
                C1 = MFMA16(A[6],  B3, C1); C1 = MFMA16(A[7],  B4, C1);
                C2 = MFMA16(A[8],  B1, C2); C2 = MFMA16(A[9],  B2, C2);
                C2 = MFMA16(A[10], B3, C2); C2 = MFMA16(A[11], B4, C2);
                C3 = MFMA16(A[12], B1, C3); C3 = MFMA16(A[13], B2, C3);
                C3 = MFMA16(A[14], B3, C3); C3 = MFMA16(A[15], B4, C3);

                float Si = pick4(C0, s0, s1) + bs0;
                float Sf = pick4(C1, s0, s1) + bs1;
                float Sg = pick4(C2, s0, s1) + bs2;
                float So = pick4(C3, s0, s1) + bs3;

                float ii = fsig(Si), ff = fsig(Sf), oo = fsig(So);
                float gg = ftanh(Sg);
                cst = ff * cst + ii * gg;
                float hv = oo * ftanh(cst);
                bn[woff] = (__fp16)hv;
            }
        }
        __syncthreads();
    }

    // h2(TT-1) sits in buf parity 1, chunks 3,4. FC + sigmoid (wave 0).
    if (wave == 0) {
        const int jg = lane >> 2;   // 0..15
        float s = 0.f;
        #pragma unroll
        for (int u2 = 0; u2 < 4; ++u2) {
            const int j = jg*4 + u2;
            float hval = (float)buf[640 + (((3 + (j >> 5))*4 + bb)*4 + ((j & 31) >> 3))*8 + (j & 7)];
            s += hval * w_fc[j];
        }
        s += __shfl_xor(s, 4);
        s += __shfl_xor(s, 8);
        s += __shfl_xor(s, 16);
        s += __shfl_xor(s, 32);
        if (lane < 4) out[bbase + lane] = fsig(s + b_fc[0]);
    }
}

extern "C" void kernel_launch(void* const* d_in, const int* in_sizes, int n_in,
                              void* d_out, int out_size, void* d_ws, size_t ws_size,
                              hipStream_t stream) {
    lstm2_b4<<<dim3(64), dim3(512), 0, stream>>>(
        (const float*)d_in[0],
        (const float*)d_in[1], (const float*)d_in[2],
        (const float*)d_in[3], (const float*)d_in[4],
        (const float*)d_in[5], (const float*)d_in[6],
        (const float*)d_in[7], (const float*)d_in[8],
        (const float*)d_in[9], (const float*)d_in[10],
        (float*)d_out);
}